// Round 13
// baseline (212.422 us; speedup 1.0000x reference)
//
#include <hip/hip_runtime.h>

// Problem constants
#define BATCH 4096
#define NI 1024
#define HID 2048
#define TSTEPS 20
#define NA 45
#define TW 1024   // fused j-tile width (2 tiles over HID)
#define SROW 1032 // S row stride in bf16 elems (1024 + 8 pad)
#define MAXS 16   // max distinct alive states per batch element (proven <= 15)
#define NB 2      // batch elements per fused_mlp block

typedef __bf16 bf16x8 __attribute__((ext_vector_type(8)));
typedef float floatx4 __attribute__((ext_vector_type(4)));

struct StepMeta {
    float ac0, ac1, delta, chosen;
    int chg;    // (oldCol<<8)|newCol applied entering this state, or -1
    int dac, mult, pad;
};

__device__ __forceinline__ unsigned short f2bf(float x) {
    union { float f; unsigned int u; } un; un.f = x;
    unsigned int r = un.u + 0x7FFFu + ((un.u >> 16) & 1u);
    return (unsigned short)(r >> 16);
}

__device__ __forceinline__ float4 f4add(float4 a, float4 b) {
    return make_float4(a.x + b.x, a.y + b.y, a.z + b.z, a.w + b.w);
}

// ---------------------------------------------------------------------------
// Per-batch-element 20-step state machine (exact fp32 replication),
// COMPRESSED: emits only distinct alive states; trailing fixed point gets a
// multiplicity; post-commit steps dropped. nd <= 15 < MAXS.
// Swap (chg>=0) states are the CONTIGUOUS PREFIX 1..ns.
// ---------------------------------------------------------------------------
__device__ void scan_one(int b, const float* __restrict__ camera,
                         const int* __restrict__ fb_in, const int* __restrict__ lr_in,
                         const int* __restrict__ jp_in, const int* __restrict__ ss_in,
                         const int* __restrict__ at_in, StepMeta* __restrict__ meta,
                         int2* __restrict__ hdr) {
    float cam0 = camera[2 * b], cam1 = camera[2 * b + 1];
    int afb = fb_in[b], alr = lr_in[b], ajp = jp_in[b], ass = ss_in[b], aat = at_in[b];
    float ac0 = 0.f, ac1 = 0.f, delta = 0.0625f;  // MIN_DELTA = 0.5/8
    int rfb = 0, rlr = 0, rjp = 0, rss = 0, rat = 0;
    bool chosen = false;
    int cam_steps = 0;
    int chgPending = -1;
    bool camzero = (fabsf(cam0) < 1e-5f) && (fabsf(cam1) < 1e-5f);
    int nd = 0, aliveTot = 0;
    float lac0 = 0.f, lac1 = 0.f, ldelta = 0.f, lchosen = 0.f;
    int ldac = -1000;
    for (int t = 0; t < TSTEPS; t++) {
        StepMeta m;
        m.ac0 = ac0; m.ac1 = ac1; m.delta = delta; m.chosen = chosen ? 1.f : 0.f;
        m.chg = chgPending; chgPending = -1;
        bool commit = (camzero || cam_steps >= 6) &&
                      rfb == afb && rlr == alr && rjp == ajp && rss == ass && rat == aat;
        int dac = 0; bool modified = commit;
        if (!modified && rfb != afb) { dac = (afb == 0 ? rfb - 1 + 6  : afb - 1 + 6 ); chgPending = ((2  + rfb) << 8) | (2  + afb); rfb = afb; modified = true; }
        if (!modified && rlr != alr) { dac = (alr == 0 ? rlr - 1 + 8  : alr - 1 + 8 ); chgPending = ((5  + rlr) << 8) | (5  + alr); rlr = alr; modified = true; }
        if (!modified && rjp != ajp) { dac = (ajp == 0 ? rjp - 1 + 10 : ajp - 1 + 10); chgPending = ((8  + rjp) << 8) | (8  + ajp); rjp = ajp; modified = true; }
        if (!modified && rss != ass) { dac = (ass == 0 ? rss - 1 + 11 : ass - 1 + 11); chgPending = ((10 + rss) << 8) | (10 + ass); rss = ass; modified = true; }
        if (!modified && rat != aat) { dac = (aat == 0 ? rat - 1 + 14 : aat - 1 + 14); chgPending = ((14 + rat) << 8) | (14 + aat); rat = aat; modified = true; }
        // NOTE: reference compares BOTH cam0 and cam1 against ac0 (replicated as-is)
        if (!modified && !chosen &&
            (fabsf(cam0 - ac0) > delta * 2.f || fabsf(cam1 - ac0) > delta * 2.f)) {
            dac = 5; delta = fminf(delta * 2.f, 0.5f); modified = true;
        }
        if (!modified) {
            bool incX = cam0 >= ac0, incY = cam1 >= ac1;
            dac = 1 + (incX ? 1 : 0) + (incY ? 2 : 0);
            ac0 += incX ? delta : -delta;
            ac1 += incY ? delta : -delta;
            delta *= 0.5f;
            chosen = true;
            cam_steps++;
        }
        m.dac = dac; m.mult = 1; m.pad = 0;
        // trailing fixed-point detection: identical state => identical forever
        if (nd > 0 && m.chg < 0 && !commit &&
            m.ac0 == lac0 && m.ac1 == lac1 && m.delta == ldelta &&
            m.chosen == lchosen && dac == ldac) {
            meta[b * MAXS + nd - 1].mult = 1 + (TSTEPS - t);
            aliveTot += (TSTEPS - t);
            break;
        }
        meta[b * MAXS + nd] = m;
        lac0 = m.ac0; lac1 = m.ac1; ldelta = m.delta; lchosen = m.chosen; ldac = dac;
        nd++; aliveTot++;
        if (commit) break;  // all remaining steps dead (alive=0 -> ce masked)
    }
    hdr[b] = make_int2(nd, aliveTot);
}

// ---------------------------------------------------------------------------
// Merged prep: convert_fc (blocks [0,4096)), transpose_w1 ([4096,6144)),
// convert_w2 ([6144,6272), 128-way parallel), scan FSM ([6272,6288)).
// ---------------------------------------------------------------------------
__global__ void prep_kernel(const float* __restrict__ fc, unsigned short* __restrict__ Ab,
                            const float* __restrict__ W1, unsigned short* __restrict__ Wt,
                            const float* __restrict__ W2, unsigned short* __restrict__ W2T,
                            const float* __restrict__ camera,
                            const int* __restrict__ fb_in, const int* __restrict__ lr_in,
                            const int* __restrict__ jp_in, const int* __restrict__ ss_in,
                            const int* __restrict__ at_in, StepMeta* __restrict__ meta,
                            int2* __restrict__ hdr) {
    __shared__ float tile[32][33];
    int bid = blockIdx.x, tid = threadIdx.x;
    if (bid < 4096) {
        int idx = bid * 256 + tid;  // covers BATCH*NI/4
        float4 v = ((const float4*)fc)[idx];
        ushort4 o;
        o.x = f2bf(v.x); o.y = f2bf(v.y); o.z = f2bf(v.z); o.w = f2bf(v.w);
        ((ushort4*)Ab)[idx] = o;
    } else if (bid < 6144) {
        int b2 = bid - 4096;
        int k0 = (b2 & 31) * 32, n0 = (b2 >> 5) * 32;
        int tx = tid & 31, ty = tid >> 5;  // (32, 8)
        for (int i = 0; i < 4; i++)
            tile[ty + 8 * i][tx] = W1[(size_t)(k0 + ty + 8 * i) * HID + n0 + tx];
        __syncthreads();
        for (int i = 0; i < 4; i++) {
            int n = ty + 8 * i;
            Wt[(size_t)(n0 + n) * NI + k0 + tx] = f2bf(tile[tx][n]);
        }
    } else if (bid < 6272) {
        int bid2 = bid - 6144;                 // 0..127
        int k = bid2 * 16 + (tid >> 4);        // 0..2047
        int nn = tid & 15;
#pragma unroll
        for (int i = 0; i < 3; i++) {
            int n = nn * 3 + i;                // 0..47
            W2T[(size_t)n * HID + k] = (n < NA) ? f2bf(W2[(size_t)k * NA + n]) : (unsigned short)0;
        }
    } else {
        int b = (bid - 6272) * 256 + tid;      // 0..4095
        scan_one(b, camera, fb_in, lr_in, jp_in, ss_in, at_in, meta, hdr);
    }
}

// ---------------------------------------------------------------------------
// GEMM: base[4096][2048] = A @ W1[:1024] (bf16 MFMA) + t=0-constant
// epilogue. 128x64 tile, 256 threads / 4 waves, 1024 blocks = 4 blocks/CU.
// R13: T1 XCD-AWARE BIJECTIVE REMAP. Default dispatch round-robins
// consecutive blocks across the 8 per-XCD L2s, so the 384 MB of A/B panel
// re-reads (A panels x32, B panels x32) replicate into all 8 L2s and
// stream from L3. Remap (1024 % 8 == 0, bijective): xcd = bid % 8 owns the
// 2D chunk bm in [xm*8,+8) x bn in [xn*16,+16), (xm,xn) = (xcd>>1, xcd&1).
// Per-XCD working set = A 2 MB + B 2 MB = 4 MB = one L2 -> re-reads hit L2.
// BK=64 + both-sides swizzle (rule #21) retained (absmax 0.0 in R8-R12).
// ---------------------------------------------------------------------------
__global__ __launch_bounds__(256) void gemm_base(const unsigned short* __restrict__ Ab,
                                                 const unsigned short* __restrict__ Wt,
                                                 const float* __restrict__ W1,
                                                 const float* __restrict__ b1,
                                                 float* __restrict__ C) {
    __shared__ __align__(16) __bf16 At[128 * 64];   // 16 KB
    __shared__ __align__(16) __bf16 Bt[64 * 64];    //  8 KB
    // XCD-aware remap (see header comment)
    int bid = blockIdx.y * gridDim.x + blockIdx.x;  // 0..1023
    int xcd = bid & 7, chunk = bid >> 3;            // chunk 0..127
    int xm = xcd >> 1, xn = xcd & 1;
    int bm = xm * 8 + (chunk >> 4);                 // 0..31
    int bn = xn * 16 + (chunk & 15);                // 0..31
    int m0 = bm * 128, n0 = bn * 64;
    int tid = threadIdx.x;
    int wave = tid >> 6, lane = tid & 63;
    int wr = wave >> 1, wc = wave & 1;           // 2 x 2 wave grid
    int l15 = lane & 15, q = lane >> 4;
    floatx4 acc[4][2];
    for (int a = 0; a < 4; a++) for (int c = 0; c < 2; c++) acc[a][c] = (floatx4){0.f, 0.f, 0.f, 0.f};
    for (int k0 = 0; k0 < NI; k0 += 64) {
        __syncthreads();
#pragma unroll
        for (int i = 0; i < 4; i++) {              // A: 1024 16B-chunks
            int c = i * 256 + tid;
            int row = c >> 3;                      // 0..127
            int part = (c & 7) ^ (row & 7);        // pre-swizzled source slot
            const unsigned short* gA = &Ab[(size_t)(m0 + row) * NI + k0 + part * 8];
            __builtin_amdgcn_global_load_lds(
                (const __attribute__((address_space(1))) unsigned int*)gA,
                (__attribute__((address_space(3))) unsigned int*)&At[c * 8], 16, 0, 0);
        }
#pragma unroll
        for (int i = 0; i < 2; i++) {              // B: 512 16B-chunks
            int c = i * 256 + tid;
            int row = c >> 3;                      // 0..63
            int part = (c & 7) ^ (row & 7);
            const unsigned short* gB = &Wt[(size_t)(n0 + row) * NI + k0 + part * 8];
            __builtin_amdgcn_global_load_lds(
                (const __attribute__((address_space(1))) unsigned int*)gB,
                (__attribute__((address_space(3))) unsigned int*)&Bt[c * 8], 16, 0, 0);
        }
        __syncthreads();
#pragma unroll
        for (int ks = 0; ks < 2; ks++) {
            bf16x8 af[4], bf[2];
            for (int mr = 0; mr < 4; mr++) {
                int row = wr * 64 + mr * 16 + l15;
                int idx = (row * 64 + ks * 32 + q * 8) ^ ((row & 7) << 3);
                af[mr] = *(const bf16x8*)&At[idx];
            }
            for (int nc = 0; nc < 2; nc++) {
                int row = wc * 32 + nc * 16 + l15;
                int idx = (row * 64 + ks * 32 + q * 8) ^ ((row & 7) << 3);
                bf[nc] = *(const bf16x8*)&Bt[idx];
            }
            for (int mr = 0; mr < 4; mr++)
                for (int nc = 0; nc < 2; nc++)
                    acc[mr][nc] = __builtin_amdgcn_mfma_f32_16x16x32_bf16(af[mr], bf[nc], acc[mr][nc], 0, 0, 0);
        }
    }
    for (int nc = 0; nc < 2; nc++) {
        int col = n0 + wc * 32 + nc * 16 + l15;
        const float* We = W1 + (size_t)NI * HID + col;
        float cv = b1[col] + We[2 * HID] + We[5 * HID] + We[8 * HID] + We[10 * HID]
                 + We[14 * HID] + 0.0625f * We[46 * HID];
        for (int mr = 0; mr < 4; mr++)
            for (int r = 0; r < 4; r++) {
                int row = m0 + wr * 64 + mr * 16 + q * 4 + r;
                C[(size_t)row * HID + col] = acc[mr][nc][r] + cv;
            }
    }
}

// ---------------------------------------------------------------------------
// Fused MLP + CE over COMPRESSED states, NB=2 batch elements per block.
// R10 structure (99.7 us, best-measured): TW=1024 / 2 j-tiles / 4 columns
// per thread (float4). Phase B: M=32 tile, K split across 8 waves.
// __launch_bounds__(512, 2): VGPR cap 256 — R8 showed aggressive caps force
// catastrophic spill (WRITE_SIZE is the tripwire; must stay ~64 KB).
// ---------------------------------------------------------------------------
__global__ __launch_bounds__(512, 2) void fused_mlp(const float* __restrict__ base,
                                                 const float* __restrict__ W1,
                                                 const unsigned short* __restrict__ W2T,
                                                 const float* __restrict__ b2,
                                                 const StepMeta* __restrict__ meta,
                                                 const int2* __restrict__ hdr,
                                                 float* __restrict__ loss_out) {
    __shared__ __align__(16) __bf16 S[NB * MAXS * SROW];   // 66,048 B; pad rows zero
    __shared__ __align__(16) float4 u4s[NB][MAXS];         // (ac0, ac1, delta-d0, chosen)
    __shared__ int chgs[NB][MAXS], dacsS[NB][MAXS], multsS[NB][MAXS];
    __shared__ int swapL[NB][5], nsS[NB], ndS[NB], atS[NB];
    __shared__ float b2s[48];
    __shared__ float ceArr[NB][MAXS];
    __shared__ float pmax[NB][MAXS][12], psum[NB][MAXS][12], mxS[NB][MAXS];

    int bp = blockIdx.x, tid = threadIdx.x;
    int tg = tid >> 8, tl = tid & 255;           // group (=b within pair), local tid
    int wave = tid >> 6, lane = tid & 63, l15 = lane & 15, q = lane >> 4;

    if (tl == 0) {
        int2 hd = hdr[bp * NB + tg];
        ndS[tg] = hd.x; atS[tg] = hd.y;
    }
    if (tl < MAXS) {
        StepMeta m = meta[(size_t)(bp * NB + tg) * MAXS + tl];
        u4s[tg][tl] = make_float4(m.ac0, m.ac1, m.delta - 0.0625f, m.chosen);
        chgs[tg][tl] = m.chg; dacsS[tg][tl] = m.dac; multsS[tg][tl] = m.mult;
    }
    if (tid >= 64 && tid < 112) {
        int n = tid - 64;
        b2s[n] = (n < NA) ? b2[n] : 0.f;
    }
    __syncthreads();
    if (tl == 0) {
        int ns = 0, nd = ndS[tg];
        for (int s = 0; s < nd; s++)
            if (chgs[tg][s] >= 0) swapL[tg][ns++] = chgs[tg][s];
        nsS[tg] = ns;
        for (; ns < 5; ns++) swapL[tg][ns] = 0;
    }
    // zero the MFMA padding rows (row = 2064 B = 129 uint4)
    {
        int nd0 = ndS[0], nd1 = ndS[1];
        uint4 zz = make_uint4(0, 0, 0, 0);
        uint4* z0 = (uint4*)&S[(size_t)nd0 * SROW];
        int n0 = (MAXS - nd0) * 129;
        for (int i = tid; i < n0; i += 512) z0[i] = zz;
        uint4* z1 = (uint4*)&S[(size_t)(MAXS + nd1) * SROW];
        int n1 = (MAXS - nd1) * 129;
        for (int i = tid; i < n1; i += 512) z1[i] = zz;
    }
    __syncthreads();

    const float* Wx = W1 + (size_t)NI * HID;
    const __bf16* Wb = (const __bf16*)W2T;
    floatx4 acc[2][3];                           // [M-tile(=element)][n-tile]
    for (int a = 0; a < 2; a++) for (int c = 0; c < 3; c++) acc[a][c] = (floatx4){0.f, 0.f, 0.f, 0.f};

    int nd = __builtin_amdgcn_readfirstlane(ndS[tg]);
    int ns = __builtin_amdgcn_readfirstlane(nsS[tg]);
    int cA = __builtin_amdgcn_readfirstlane(swapL[tg][0]);
    int cB = __builtin_amdgcn_readfirstlane(swapL[tg][1]);
    int cC = __builtin_amdgcn_readfirstlane(swapL[tg][2]);
    int cD = __builtin_amdgcn_readfirstlane(swapL[tg][3]);
    int cE = __builtin_amdgcn_readfirstlane(swapL[tg][4]);

    for (int jt = 0; jt < 2; jt++) {
        if (jt) __syncthreads();                 // phase-B readers of prev tile done
        int j = jt * TW + 4 * tl;
        // hoisted loads (float4, 4 columns): w-vectors, base, ALL swap rows
        float4 w0  = *(const float4*)&Wx[j];
        float4 w1  = *(const float4*)&Wx[HID + j];
        float4 wdl = *(const float4*)&Wx[46 * HID + j];
        float4 wch = *(const float4*)&Wx[47 * HID + j];
        float4 hb  = *(const float4*)&base[(size_t)(bp * NB + tg) * HID + j];
        float4 dA = {0,0,0,0}, dB = {0,0,0,0}, dC = {0,0,0,0}, dD = {0,0,0,0}, dE = {0,0,0,0};
        if (ns > 0) { float4 n_ = *(const float4*)&Wx[(size_t)(cA & 255) * HID + j], o_ = *(const float4*)&Wx[(size_t)(cA >> 8) * HID + j];
                      dA = make_float4(n_.x - o_.x, n_.y - o_.y, n_.z - o_.z, n_.w - o_.w); }
        if (ns > 1) { float4 n_ = *(const float4*)&Wx[(size_t)(cB & 255) * HID + j], o_ = *(const float4*)&Wx[(size_t)(cB >> 8) * HID + j];
                      dB = make_float4(n_.x - o_.x, n_.y - o_.y, n_.z - o_.z, n_.w - o_.w); }
        if (ns > 2) { float4 n_ = *(const float4*)&Wx[(size_t)(cC & 255) * HID + j], o_ = *(const float4*)&Wx[(size_t)(cC >> 8) * HID + j];
                      dC = make_float4(n_.x - o_.x, n_.y - o_.y, n_.z - o_.z, n_.w - o_.w); }
        if (ns > 3) { float4 n_ = *(const float4*)&Wx[(size_t)(cD & 255) * HID + j], o_ = *(const float4*)&Wx[(size_t)(cD >> 8) * HID + j];
                      dD = make_float4(n_.x - o_.x, n_.y - o_.y, n_.z - o_.z, n_.w - o_.w); }
        if (ns > 4) { float4 n_ = *(const float4*)&Wx[(size_t)(cE & 255) * HID + j], o_ = *(const float4*)&Wx[(size_t)(cE >> 8) * HID + j];
                      dE = make_float4(n_.x - o_.x, n_.y - o_.y, n_.z - o_.z, n_.w - o_.w); }

        // one silu state over 4 columns: h = ((b + u.x*w0) + (u.y*w1 + u.z*wdl)) + u.w*wch
        auto compute1 = [&](int s, float4 b) {
            float4 u = u4s[tg][s];
            float h0 = fmaf(u.w, wch.x, fmaf(u.x, w0.x, b.x)) + fmaf(u.z, wdl.x, u.y * w1.x);
            float h1 = fmaf(u.w, wch.y, fmaf(u.x, w0.y, b.y)) + fmaf(u.z, wdl.y, u.y * w1.y);
            float h2 = fmaf(u.w, wch.z, fmaf(u.x, w0.z, b.z)) + fmaf(u.z, wdl.z, u.y * w1.z);
            float h3 = fmaf(u.w, wch.w, fmaf(u.x, w0.w, b.w)) + fmaf(u.z, wdl.w, u.y * w1.w);
            float s0 = h0 * __builtin_amdgcn_rcpf(1.f + __expf(-h0));
            float s1 = h1 * __builtin_amdgcn_rcpf(1.f + __expf(-h1));
            float s2 = h2 * __builtin_amdgcn_rcpf(1.f + __expf(-h2));
            float s3 = h3 * __builtin_amdgcn_rcpf(1.f + __expf(-h3));
            union { uint2 v; __bf16 h[4]; } pk;
            pk.h[0] = (__bf16)s0; pk.h[1] = (__bf16)s1;   // v_cvt_pk_bf16_f32 (RNE)
            pk.h[2] = (__bf16)s2; pk.h[3] = (__bf16)s3;
            *(uint2*)&S[(size_t)(tg * MAXS + s) * SROW + 4 * tl] = pk.v;
        };

        // swap-prefix states (contiguous, compile-time unrolled; ns uniform)
        float4 sw = {0,0,0,0};
        compute1(0, hb);
        if (ns > 0) { sw = f4add(sw, dA); compute1(1, f4add(hb, sw)); }
        if (ns > 1) { sw = f4add(sw, dB); compute1(2, f4add(hb, sw)); }
        if (ns > 2) { sw = f4add(sw, dC); compute1(3, f4add(hb, sw)); }
        if (ns > 3) { sw = f4add(sw, dD); compute1(4, f4add(hb, sw)); }
        if (ns > 4) { sw = f4add(sw, dE); compute1(5, f4add(hb, sw)); }
        // tail states (no swaps): 2 per iteration -> 8 independent silu chains
        float4 bxv = f4add(hb, sw);
        int s = ns + 1;
        for (; s + 1 < nd; s += 2) {
            compute1(s, bxv);
            compute1(s + 1, bxv);
        }
        if (s < nd) compute1(s, bxv);

        __syncthreads();
        // Phase B: all 8 waves split K; wave w -> k-chunks {w, w+8, w+16, w+24},
        // M=32 rows (both elements) per B-fragment load.
#pragma unroll
        for (int i = 0; i < 4; i++) {
            int kc = (wave + 8 * i) * 32 + q * 8;            // 0..1016
            bf16x8 a0 = *(const bf16x8*)&S[(size_t)l15 * SROW + kc];
            bf16x8 a1 = *(const bf16x8*)&S[(size_t)(MAXS + l15) * SROW + kc];
            int kg = jt * TW + kc;
            bf16x8 b0  = *(const bf16x8*)&Wb[(size_t)l15 * HID + kg];
            bf16x8 b1v = *(const bf16x8*)&Wb[(size_t)(16 + l15) * HID + kg];
            bf16x8 b2v = *(const bf16x8*)&Wb[(size_t)(32 + l15) * HID + kg];
            acc[0][0] = __builtin_amdgcn_mfma_f32_16x16x32_bf16(a0, b0,  acc[0][0], 0, 0, 0);
            acc[0][1] = __builtin_amdgcn_mfma_f32_16x16x32_bf16(a0, b1v, acc[0][1], 0, 0, 0);
            acc[0][2] = __builtin_amdgcn_mfma_f32_16x16x32_bf16(a0, b2v, acc[0][2], 0, 0, 0);
            acc[1][0] = __builtin_amdgcn_mfma_f32_16x16x32_bf16(a1, b0,  acc[1][0], 0, 0, 0);
            acc[1][1] = __builtin_amdgcn_mfma_f32_16x16x32_bf16(a1, b1v, acc[1][1], 0, 0, 0);
            acc[1][2] = __builtin_amdgcn_mfma_f32_16x16x32_bf16(a1, b2v, acc[1][2], 0, 0, 0);
        }
    }
    __syncthreads();
    // 2-stage cross-wave reduction in dead S. Partial layout:
    // [wv(0..3)][mt(0..1)][row16][48] floats = 6144 floats (24,576 B).
    float* logitsP = (float*)S;
    float* logitsF = (float*)S + 6144;           // 1536 floats, ends at 30,720 B
    if (wave >= 4) {
        int wv = wave - 4;
#pragma unroll
        for (int mt = 0; mt < 2; mt++)
#pragma unroll
            for (int nt = 0; nt < 3; nt++)
#pragma unroll
                for (int r = 0; r < 4; r++)
                    logitsP[(size_t)(wv * 2 + mt) * 768 + (q * 4 + r) * 48 + nt * 16 + l15] = acc[mt][nt][r];
    }
    __syncthreads();
    if (wave < 4) {
        int wv = wave;
#pragma unroll
        for (int mt = 0; mt < 2; mt++)
#pragma unroll
            for (int nt = 0; nt < 3; nt++)
#pragma unroll
                for (int r = 0; r < 4; r++) {
                    size_t idx = (size_t)(wv * 2 + mt) * 768 + (q * 4 + r) * 48 + nt * 16 + l15;
                    logitsP[idx] += acc[mt][nt][r];
                }
    }
    __syncthreads();
    // final sum over 4 partials, 384 threads (192 per element)
    int tg2 = tid / 192, tl2 = tid - tg2 * 192;
    int tE = tl2 / 12, gE = tl2 - tE * 12;
    if (tid < 384) {
        const float4* P0 = (const float4*)(logitsP + (size_t)(0 * 2 + tg2) * 768);
        const float4* P1 = (const float4*)(logitsP + (size_t)(1 * 2 + tg2) * 768);
        const float4* P2 = (const float4*)(logitsP + (size_t)(2 * 2 + tg2) * 768);
        const float4* P3 = (const float4*)(logitsP + (size_t)(3 * 2 + tg2) * 768);
        float4 p0 = P0[tl2], p1 = P1[tl2], p2 = P2[tl2], p3 = P3[tl2];
        float4 bb = *(const float4*)&b2s[gE * 4];
        float4 r;
        r.x = p0.x + p1.x + p2.x + p3.x + bb.x;
        r.y = p0.y + p1.y + p2.y + p3.y + bb.y;
        r.z = p0.z + p1.z + p2.z + p3.z + bb.z;
        r.w = p0.w + p1.w + p2.w + p3.w + bb.w;
        ((float4*)(logitsF + tg2 * 768))[tl2] = r;
        float lm = (gE == 11) ? r.x : fmaxf(fmaxf(r.x, r.y), fmaxf(r.z, r.w));
        pmax[tg2][tE][gE] = lm;
    }
    __syncthreads();
    if (tid < 384 && gE == 0) {
        float m = pmax[tg2][tE][0];
        for (int i = 1; i < 12; i++) m = fmaxf(m, pmax[tg2][tE][i]);
        mxS[tg2][tE] = m;
    }
    __syncthreads();
    if (tid < 384) {
        float m = mxS[tg2][tE];
        float4 v = ((const float4*)(logitsF + tg2 * 768))[tl2];
        float s;
        if (gE == 11) s = __expf(v.x - m);
        else s = __expf(v.x - m) + __expf(v.y - m) + __expf(v.z - m) + __expf(v.w - m);
        psum[tg2][tE][gE] = s;
    }
    __syncthreads();
    if (tl < nd) {
        float ssum = 0.f;
        for (int i = 0; i < 12; i++) ssum += psum[tg][tl][i];
        float m = mxS[tg][tl];
        int dac = dacsS[tg][tl];
        float ld = logitsF[tg * 768 + tl * 48 + dac];
        float ce = -(ld - m - logf(ssum));
        ceArr[tg][tl] = ce * (float)multsS[tg][tl];
    }
    __syncthreads();
    if (tl == 0) {
        float s = 0.f;
        for (int t = 0; t < nd; t++) s += ceArr[tg][t];
        loss_out[bp * NB + tg] = s / (float)atS[tg];
    }
}

// ---------------------------------------------------------------------------
// Deterministic final reduction over 4096 per-b losses
// ---------------------------------------------------------------------------
__global__ void reduce_loss(const float* __restrict__ loss, float* __restrict__ out) {
    int tid = threadIdx.x;  // 256
    float s = 0.f;
    for (int i = tid; i < BATCH; i += 256) s += loss[i];
    for (int off = 32; off > 0; off >>= 1) s += __shfl_down(s, off, 64);
    __shared__ float wsum[4];
    if ((tid & 63) == 0) wsum[tid >> 6] = s;
    __syncthreads();
    if (tid == 0) out[0] = (wsum[0] + wsum[1] + wsum[2] + wsum[3]) * (1.0f / (float)BATCH);
}

// ---------------------------------------------------------------------------
extern "C" void kernel_launch(void* const* d_in, const int* in_sizes, int n_in,
                              void* d_out, int out_size, void* d_ws, size_t ws_size,
                              hipStream_t stream) {
    const float* fc_input = (const float*)d_in[0];
    const float* camera   = (const float*)d_in[1];
    const int*   fb       = (const int*)d_in[2];
    const int*   lr       = (const int*)d_in[3];
    const int*   jp       = (const int*)d_in[4];
    const int*   ss       = (const int*)d_in[5];
    const int*   at       = (const int*)d_in[6];
    const float* W1       = (const float*)d_in[7];
    const float* b1       = (const float*)d_in[8];
    const float* W2       = (const float*)d_in[9];
    const float* b2       = (const float*)d_in[10];
    float* out = (float*)d_out;

    char* ws = (char*)d_ws;
    unsigned short* Ab   = (unsigned short*)(ws);                       //  8,388,608 B
    unsigned short* Wt   = (unsigned short*)(ws + 8388608);             //  4,194,304 B
    float*          baseB= (float*)(ws + 12582912);                     // 33,554,432 B
    StepMeta*       meta = (StepMeta*)(ws + 46137344);                  //  2,097,152 B
    int2*           hdr  = (int2*)(ws + 48234496);                      //     32,768 B
    float*          lossB= (float*)(ws + 48267264);                     //     16,384 B
    unsigned short* W2T  = (unsigned short*)(ws + 48283648);            //    196,608 B

    prep_kernel<<<4096 + 2048 + 128 + 16, 256, 0, stream>>>(fc_input, Ab, W1, Wt, W2, W2T,
                                                            camera, fb, lr, jp, ss, at, meta, hdr);
    gemm_base<<<dim3(HID / 64, BATCH / 128), 256, 0, stream>>>(Ab, Wt, W1, b1, baseB);
    fused_mlp<<<BATCH / NB, 512, 0, stream>>>(baseB, W1, W2T, b2, meta, hdr, lossB);
    reduce_loss<<<1, 256, 0, stream>>>(lossB, out);
}

// Round 14
// 208.811 us; speedup vs baseline: 1.0173x; 1.0173x over previous
//
#include <hip/hip_runtime.h>

// Problem constants
#define BATCH 4096
#define NI 1024
#define HID 2048
#define TSTEPS 20
#define NA 45
#define TW 1024   // fused j-tile width (2 tiles over HID)
#define SROW 1032 // S row stride in bf16 elems (1024 + 8 pad)
#define MAXS 16   // max distinct alive states per batch element (proven <= 15)
#define NB 2      // batch elements per fused_mlp block

typedef __bf16 bf16x8 __attribute__((ext_vector_type(8)));
typedef float floatx4 __attribute__((ext_vector_type(4)));

struct StepMeta {
    float ac0, ac1, delta, chosen;
    int chg;    // (oldCol<<8)|newCol applied entering this state, or -1
    int dac, mult, pad;
};

__device__ __forceinline__ unsigned short f2bf(float x) {
    union { float f; unsigned int u; } un; un.f = x;
    unsigned int r = un.u + 0x7FFFu + ((un.u >> 16) & 1u);
    return (unsigned short)(r >> 16);
}

__device__ __forceinline__ float4 f4add(float4 a, float4 b) {
    return make_float4(a.x + b.x, a.y + b.y, a.z + b.z, a.w + b.w);
}

// ---------------------------------------------------------------------------
// Per-batch-element 20-step state machine (exact fp32 replication),
// COMPRESSED: emits only distinct alive states; trailing fixed point gets a
// multiplicity; post-commit steps dropped. nd <= 15 < MAXS.
// Swap (chg>=0) states are the CONTIGUOUS PREFIX 1..ns.
// ---------------------------------------------------------------------------
__device__ void scan_one(int b, const float* __restrict__ camera,
                         const int* __restrict__ fb_in, const int* __restrict__ lr_in,
                         const int* __restrict__ jp_in, const int* __restrict__ ss_in,
                         const int* __restrict__ at_in, StepMeta* __restrict__ meta,
                         int2* __restrict__ hdr) {
    float cam0 = camera[2 * b], cam1 = camera[2 * b + 1];
    int afb = fb_in[b], alr = lr_in[b], ajp = jp_in[b], ass = ss_in[b], aat = at_in[b];
    float ac0 = 0.f, ac1 = 0.f, delta = 0.0625f;  // MIN_DELTA = 0.5/8
    int rfb = 0, rlr = 0, rjp = 0, rss = 0, rat = 0;
    bool chosen = false;
    int cam_steps = 0;
    int chgPending = -1;
    bool camzero = (fabsf(cam0) < 1e-5f) && (fabsf(cam1) < 1e-5f);
    int nd = 0, aliveTot = 0;
    float lac0 = 0.f, lac1 = 0.f, ldelta = 0.f, lchosen = 0.f;
    int ldac = -1000;
    for (int t = 0; t < TSTEPS; t++) {
        StepMeta m;
        m.ac0 = ac0; m.ac1 = ac1; m.delta = delta; m.chosen = chosen ? 1.f : 0.f;
        m.chg = chgPending; chgPending = -1;
        bool commit = (camzero || cam_steps >= 6) &&
                      rfb == afb && rlr == alr && rjp == ajp && rss == ass && rat == aat;
        int dac = 0; bool modified = commit;
        if (!modified && rfb != afb) { dac = (afb == 0 ? rfb - 1 + 6  : afb - 1 + 6 ); chgPending = ((2  + rfb) << 8) | (2  + afb); rfb = afb; modified = true; }
        if (!modified && rlr != alr) { dac = (alr == 0 ? rlr - 1 + 8  : alr - 1 + 8 ); chgPending = ((5  + rlr) << 8) | (5  + alr); rlr = alr; modified = true; }
        if (!modified && rjp != ajp) { dac = (ajp == 0 ? rjp - 1 + 10 : ajp - 1 + 10); chgPending = ((8  + rjp) << 8) | (8  + ajp); rjp = ajp; modified = true; }
        if (!modified && rss != ass) { dac = (ass == 0 ? rss - 1 + 11 : ass - 1 + 11); chgPending = ((10 + rss) << 8) | (10 + ass); rss = ass; modified = true; }
        if (!modified && rat != aat) { dac = (aat == 0 ? rat - 1 + 14 : aat - 1 + 14); chgPending = ((14 + rat) << 8) | (14 + aat); rat = aat; modified = true; }
        // NOTE: reference compares BOTH cam0 and cam1 against ac0 (replicated as-is)
        if (!modified && !chosen &&
            (fabsf(cam0 - ac0) > delta * 2.f || fabsf(cam1 - ac0) > delta * 2.f)) {
            dac = 5; delta = fminf(delta * 2.f, 0.5f); modified = true;
        }
        if (!modified) {
            bool incX = cam0 >= ac0, incY = cam1 >= ac1;
            dac = 1 + (incX ? 1 : 0) + (incY ? 2 : 0);
            ac0 += incX ? delta : -delta;
            ac1 += incY ? delta : -delta;
            delta *= 0.5f;
            chosen = true;
            cam_steps++;
        }
        m.dac = dac; m.mult = 1; m.pad = 0;
        // trailing fixed-point detection: identical state => identical forever
        if (nd > 0 && m.chg < 0 && !commit &&
            m.ac0 == lac0 && m.ac1 == lac1 && m.delta == ldelta &&
            m.chosen == lchosen && dac == ldac) {
            meta[b * MAXS + nd - 1].mult = 1 + (TSTEPS - t);
            aliveTot += (TSTEPS - t);
            break;
        }
        meta[b * MAXS + nd] = m;
        lac0 = m.ac0; lac1 = m.ac1; ldelta = m.delta; lchosen = m.chosen; ldac = dac;
        nd++; aliveTot++;
        if (commit) break;  // all remaining steps dead (alive=0 -> ce masked)
    }
    hdr[b] = make_int2(nd, aliveTot);
}

// ---------------------------------------------------------------------------
// Merged prep: convert_fc (blocks [0,4096)), transpose_w1 ([4096,6144)),
// convert_w2 ([6144,6272), 128-way parallel), scan FSM ([6272,6288)).
// ---------------------------------------------------------------------------
__global__ void prep_kernel(const float* __restrict__ fc, unsigned short* __restrict__ Ab,
                            const float* __restrict__ W1, unsigned short* __restrict__ Wt,
                            const float* __restrict__ W2, unsigned short* __restrict__ W2T,
                            const float* __restrict__ camera,
                            const int* __restrict__ fb_in, const int* __restrict__ lr_in,
                            const int* __restrict__ jp_in, const int* __restrict__ ss_in,
                            const int* __restrict__ at_in, StepMeta* __restrict__ meta,
                            int2* __restrict__ hdr) {
    __shared__ float tile[32][33];
    int bid = blockIdx.x, tid = threadIdx.x;
    if (bid < 4096) {
        int idx = bid * 256 + tid;  // covers BATCH*NI/4
        float4 v = ((const float4*)fc)[idx];
        ushort4 o;
        o.x = f2bf(v.x); o.y = f2bf(v.y); o.z = f2bf(v.z); o.w = f2bf(v.w);
        ((ushort4*)Ab)[idx] = o;
    } else if (bid < 6144) {
        int b2 = bid - 4096;
        int k0 = (b2 & 31) * 32, n0 = (b2 >> 5) * 32;
        int tx = tid & 31, ty = tid >> 5;  // (32, 8)
        for (int i = 0; i < 4; i++)
            tile[ty + 8 * i][tx] = W1[(size_t)(k0 + ty + 8 * i) * HID + n0 + tx];
        __syncthreads();
        for (int i = 0; i < 4; i++) {
            int n = ty + 8 * i;
            Wt[(size_t)(n0 + n) * NI + k0 + tx] = f2bf(tile[tx][n]);
        }
    } else if (bid < 6272) {
        int bid2 = bid - 6144;                 // 0..127
        int k = bid2 * 16 + (tid >> 4);        // 0..2047
        int nn = tid & 15;
#pragma unroll
        for (int i = 0; i < 3; i++) {
            int n = nn * 3 + i;                // 0..47
            W2T[(size_t)n * HID + k] = (n < NA) ? f2bf(W2[(size_t)k * NA + n]) : (unsigned short)0;
        }
    } else {
        int b = (bid - 6272) * 256 + tid;      // 0..4095
        scan_one(b, camera, fb_in, lr_in, jp_in, ss_in, at_in, meta, hdr);
    }
}

// ---------------------------------------------------------------------------
// GEMM: base[4096][2048] = A @ W1[:1024] (bf16 MFMA) + t=0-constant
// epilogue. R12 configuration (measured best, 208.9 total): 128x64 tile,
// 256 threads / 4 waves (2x2), linear dispatch, 1024 blocks = 4 blocks/CU.
// XCD remap REVERTED (R13: -3.5 us regression). BK=64 + both-sides swizzle
// (rule #21) retained: linear gload_lds dest + pre-swizzled SOURCE chunk
// (part ^= row&7) + matching XOR on the read. absmax 0.0 since R8.
// ---------------------------------------------------------------------------
__global__ __launch_bounds__(256) void gemm_base(const unsigned short* __restrict__ Ab,
                                                 const unsigned short* __restrict__ Wt,
                                                 const float* __restrict__ W1,
                                                 const float* __restrict__ b1,
                                                 float* __restrict__ C) {
    __shared__ __align__(16) __bf16 At[128 * 64];   // 16 KB
    __shared__ __align__(16) __bf16 Bt[64 * 64];    //  8 KB
    int bn = blockIdx.x, bm = blockIdx.y;
    int m0 = bm * 128, n0 = bn * 64;
    int tid = threadIdx.x;
    int wave = tid >> 6, lane = tid & 63;
    int wr = wave >> 1, wc = wave & 1;           // 2 x 2 wave grid
    int l15 = lane & 15, q = lane >> 4;
    floatx4 acc[4][2];
    for (int a = 0; a < 4; a++) for (int c = 0; c < 2; c++) acc[a][c] = (floatx4){0.f, 0.f, 0.f, 0.f};
    for (int k0 = 0; k0 < NI; k0 += 64) {
        __syncthreads();
#pragma unroll
        for (int i = 0; i < 4; i++) {              // A: 1024 16B-chunks
            int c = i * 256 + tid;
            int row = c >> 3;                      // 0..127
            int part = (c & 7) ^ (row & 7);        // pre-swizzled source slot
            const unsigned short* gA = &Ab[(size_t)(m0 + row) * NI + k0 + part * 8];
            __builtin_amdgcn_global_load_lds(
                (const __attribute__((address_space(1))) unsigned int*)gA,
                (__attribute__((address_space(3))) unsigned int*)&At[c * 8], 16, 0, 0);
        }
#pragma unroll
        for (int i = 0; i < 2; i++) {              // B: 512 16B-chunks
            int c = i * 256 + tid;
            int row = c >> 3;                      // 0..63
            int part = (c & 7) ^ (row & 7);
            const unsigned short* gB = &Wt[(size_t)(n0 + row) * NI + k0 + part * 8];
            __builtin_amdgcn_global_load_lds(
                (const __attribute__((address_space(1))) unsigned int*)gB,
                (__attribute__((address_space(3))) unsigned int*)&Bt[c * 8], 16, 0, 0);
        }
        __syncthreads();
#pragma unroll
        for (int ks = 0; ks < 2; ks++) {
            bf16x8 af[4], bf[2];
            for (int mr = 0; mr < 4; mr++) {
                int row = wr * 64 + mr * 16 + l15;
                int idx = (row * 64 + ks * 32 + q * 8) ^ ((row & 7) << 3);
                af[mr] = *(const bf16x8*)&At[idx];
            }
            for (int nc = 0; nc < 2; nc++) {
                int row = wc * 32 + nc * 16 + l15;
                int idx = (row * 64 + ks * 32 + q * 8) ^ ((row & 7) << 3);
                bf[nc] = *(const bf16x8*)&Bt[idx];
            }
            for (int mr = 0; mr < 4; mr++)
                for (int nc = 0; nc < 2; nc++)
                    acc[mr][nc] = __builtin_amdgcn_mfma_f32_16x16x32_bf16(af[mr], bf[nc], acc[mr][nc], 0, 0, 0);
        }
    }
    for (int nc = 0; nc < 2; nc++) {
        int col = n0 + wc * 32 + nc * 16 + l15;
        const float* We = W1 + (size_t)NI * HID + col;
        float cv = b1[col] + We[2 * HID] + We[5 * HID] + We[8 * HID] + We[10 * HID]
                 + We[14 * HID] + 0.0625f * We[46 * HID];
        for (int mr = 0; mr < 4; mr++)
            for (int r = 0; r < 4; r++) {
                int row = m0 + wr * 64 + mr * 16 + q * 4 + r;
                C[(size_t)row * HID + col] = acc[mr][nc][r] + cv;
            }
    }
}

// ---------------------------------------------------------------------------
// Fused MLP + CE over COMPRESSED states, NB=2 batch elements per block.
// R10 structure (99.7 us, best-measured): TW=1024 / 2 j-tiles / 4 columns
// per thread (float4). Phase B: M=32 tile, K split across 8 waves.
// __launch_bounds__(512, 2): VGPR cap 256 — R8 showed aggressive caps force
// catastrophic spill (WRITE_SIZE is the tripwire; must stay ~64 KB).
// ---------------------------------------------------------------------------
__global__ __launch_bounds__(512, 2) void fused_mlp(const float* __restrict__ base,
                                                 const float* __restrict__ W1,
                                                 const unsigned short* __restrict__ W2T,
                                                 const float* __restrict__ b2,
                                                 const StepMeta* __restrict__ meta,
                                                 const int2* __restrict__ hdr,
                                                 float* __restrict__ loss_out) {
    __shared__ __align__(16) __bf16 S[NB * MAXS * SROW];   // 66,048 B; pad rows zero
    __shared__ __align__(16) float4 u4s[NB][MAXS];         // (ac0, ac1, delta-d0, chosen)
    __shared__ int chgs[NB][MAXS], dacsS[NB][MAXS], multsS[NB][MAXS];
    __shared__ int swapL[NB][5], nsS[NB], ndS[NB], atS[NB];
    __shared__ float b2s[48];
    __shared__ float ceArr[NB][MAXS];
    __shared__ float pmax[NB][MAXS][12], psum[NB][MAXS][12], mxS[NB][MAXS];

    int bp = blockIdx.x, tid = threadIdx.x;
    int tg = tid >> 8, tl = tid & 255;           // group (=b within pair), local tid
    int wave = tid >> 6, lane = tid & 63, l15 = lane & 15, q = lane >> 4;

    if (tl == 0) {
        int2 hd = hdr[bp * NB + tg];
        ndS[tg] = hd.x; atS[tg] = hd.y;
    }
    if (tl < MAXS) {
        StepMeta m = meta[(size_t)(bp * NB + tg) * MAXS + tl];
        u4s[tg][tl] = make_float4(m.ac0, m.ac1, m.delta - 0.0625f, m.chosen);
        chgs[tg][tl] = m.chg; dacsS[tg][tl] = m.dac; multsS[tg][tl] = m.mult;
    }
    if (tid >= 64 && tid < 112) {
        int n = tid - 64;
        b2s[n] = (n < NA) ? b2[n] : 0.f;
    }
    __syncthreads();
    if (tl == 0) {
        int ns = 0, nd = ndS[tg];
        for (int s = 0; s < nd; s++)
            if (chgs[tg][s] >= 0) swapL[tg][ns++] = chgs[tg][s];
        nsS[tg] = ns;
        for (; ns < 5; ns++) swapL[tg][ns] = 0;
    }
    // zero the MFMA padding rows (row = 2064 B = 129 uint4)
    {
        int nd0 = ndS[0], nd1 = ndS[1];
        uint4 zz = make_uint4(0, 0, 0, 0);
        uint4* z0 = (uint4*)&S[(size_t)nd0 * SROW];
        int n0 = (MAXS - nd0) * 129;
        for (int i = tid; i < n0; i += 512) z0[i] = zz;
        uint4* z1 = (uint4*)&S[(size_t)(MAXS + nd1) * SROW];
        int n1 = (MAXS - nd1) * 129;
        for (int i = tid; i < n1; i += 512) z1[i] = zz;
    }
    __syncthreads();

    const float* Wx = W1 + (size_t)NI * HID;
    const __bf16* Wb = (const __bf16*)W2T;
    floatx4 acc[2][3];                           // [M-tile(=element)][n-tile]
    for (int a = 0; a < 2; a++) for (int c = 0; c < 3; c++) acc[a][c] = (floatx4){0.f, 0.f, 0.f, 0.f};

    int nd = __builtin_amdgcn_readfirstlane(ndS[tg]);
    int ns = __builtin_amdgcn_readfirstlane(nsS[tg]);
    int cA = __builtin_amdgcn_readfirstlane(swapL[tg][0]);
    int cB = __builtin_amdgcn_readfirstlane(swapL[tg][1]);
    int cC = __builtin_amdgcn_readfirstlane(swapL[tg][2]);
    int cD = __builtin_amdgcn_readfirstlane(swapL[tg][3]);
    int cE = __builtin_amdgcn_readfirstlane(swapL[tg][4]);

    for (int jt = 0; jt < 2; jt++) {
        if (jt) __syncthreads();                 // phase-B readers of prev tile done
        int j = jt * TW + 4 * tl;
        // hoisted loads (float4, 4 columns): w-vectors, base, ALL swap rows
        float4 w0  = *(const float4*)&Wx[j];
        float4 w1  = *(const float4*)&Wx[HID + j];
        float4 wdl = *(const float4*)&Wx[46 * HID + j];
        float4 wch = *(const float4*)&Wx[47 * HID + j];
        float4 hb  = *(const float4*)&base[(size_t)(bp * NB + tg) * HID + j];
        float4 dA = {0,0,0,0}, dB = {0,0,0,0}, dC = {0,0,0,0}, dD = {0,0,0,0}, dE = {0,0,0,0};
        if (ns > 0) { float4 n_ = *(const float4*)&Wx[(size_t)(cA & 255) * HID + j], o_ = *(const float4*)&Wx[(size_t)(cA >> 8) * HID + j];
                      dA = make_float4(n_.x - o_.x, n_.y - o_.y, n_.z - o_.z, n_.w - o_.w); }
        if (ns > 1) { float4 n_ = *(const float4*)&Wx[(size_t)(cB & 255) * HID + j], o_ = *(const float4*)&Wx[(size_t)(cB >> 8) * HID + j];
                      dB = make_float4(n_.x - o_.x, n_.y - o_.y, n_.z - o_.z, n_.w - o_.w); }
        if (ns > 2) { float4 n_ = *(const float4*)&Wx[(size_t)(cC & 255) * HID + j], o_ = *(const float4*)&Wx[(size_t)(cC >> 8) * HID + j];
                      dC = make_float4(n_.x - o_.x, n_.y - o_.y, n_.z - o_.z, n_.w - o_.w); }
        if (ns > 3) { float4 n_ = *(const float4*)&Wx[(size_t)(cD & 255) * HID + j], o_ = *(const float4*)&Wx[(size_t)(cD >> 8) * HID + j];
                      dD = make_float4(n_.x - o_.x, n_.y - o_.y, n_.z - o_.z, n_.w - o_.w); }
        if (ns > 4) { float4 n_ = *(const float4*)&Wx[(size_t)(cE & 255) * HID + j], o_ = *(const float4*)&Wx[(size_t)(cE >> 8) * HID + j];
                      dE = make_float4(n_.x - o_.x, n_.y - o_.y, n_.z - o_.z, n_.w - o_.w); }

        // one silu state over 4 columns: h = ((b + u.x*w0) + (u.y*w1 + u.z*wdl)) + u.w*wch
        auto compute1 = [&](int s, float4 b) {
            float4 u = u4s[tg][s];
            float h0 = fmaf(u.w, wch.x, fmaf(u.x, w0.x, b.x)) + fmaf(u.z, wdl.x, u.y * w1.x);
            float h1 = fmaf(u.w, wch.y, fmaf(u.x, w0.y, b.y)) + fmaf(u.z, wdl.y, u.y * w1.y);
            float h2 = fmaf(u.w, wch.z, fmaf(u.x, w0.z, b.z)) + fmaf(u.z, wdl.z, u.y * w1.z);
            float h3 = fmaf(u.w, wch.w, fmaf(u.x, w0.w, b.w)) + fmaf(u.z, wdl.w, u.y * w1.w);
            float s0 = h0 * __builtin_amdgcn_rcpf(1.f + __expf(-h0));
            float s1 = h1 * __builtin_amdgcn_rcpf(1.f + __expf(-h1));
            float s2 = h2 * __builtin_amdgcn_rcpf(1.f + __expf(-h2));
            float s3 = h3 * __builtin_amdgcn_rcpf(1.f + __expf(-h3));
            union { uint2 v; __bf16 h[4]; } pk;
            pk.h[0] = (__bf16)s0; pk.h[1] = (__bf16)s1;   // v_cvt_pk_bf16_f32 (RNE)
            pk.h[2] = (__bf16)s2; pk.h[3] = (__bf16)s3;
            *(uint2*)&S[(size_t)(tg * MAXS + s) * SROW + 4 * tl] = pk.v;
        };

        // swap-prefix states (contiguous, compile-time unrolled; ns uniform)
        float4 sw = {0,0,0,0};
        compute1(0, hb);
        if (ns > 0) { sw = f4add(sw, dA); compute1(1, f4add(hb, sw)); }
        if (ns > 1) { sw = f4add(sw, dB); compute1(2, f4add(hb, sw)); }
        if (ns > 2) { sw = f4add(sw, dC); compute1(3, f4add(hb, sw)); }
        if (ns > 3) { sw = f4add(sw, dD); compute1(4, f4add(hb, sw)); }
        if (ns > 4) { sw = f4add(sw, dE); compute1(5, f4add(hb, sw)); }
        // tail states (no swaps): 2 per iteration -> 8 independent silu chains
        float4 bxv = f4add(hb, sw);
        int s = ns + 1;
        for (; s + 1 < nd; s += 2) {
            compute1(s, bxv);
            compute1(s + 1, bxv);
        }
        if (s < nd) compute1(s, bxv);

        __syncthreads();
        // Phase B: all 8 waves split K; wave w -> k-chunks {w, w+8, w+16, w+24},
        // M=32 rows (both elements) per B-fragment load.
#pragma unroll
        for (int i = 0; i < 4; i++) {
            int kc = (wave + 8 * i) * 32 + q * 8;            // 0..1016
            bf16x8 a0 = *(const bf16x8*)&S[(size_t)l15 * SROW + kc];
            bf16x8 a1 = *(const bf16x8*)&S[(size_t)(MAXS + l15) * SROW + kc];
            int kg = jt * TW + kc;
            bf16x8 b0  = *(const bf16x8*)&Wb[(size_t)l15 * HID + kg];
            bf16x8 b1v = *(const bf16x8*)&Wb[(size_t)(16 + l15) * HID + kg];
            bf16x8 b2v = *(const bf16x8*)&Wb[(size_t)(32 + l15) * HID + kg];
            acc[0][0] = __builtin_amdgcn_mfma_f32_16x16x32_bf16(a0, b0,  acc[0][0], 0, 0, 0);
            acc[0][1] = __builtin_amdgcn_mfma_f32_16x16x32_bf16(a0, b1v, acc[0][1], 0, 0, 0);
            acc[0][2] = __builtin_amdgcn_mfma_f32_16x16x32_bf16(a0, b2v, acc[0][2], 0, 0, 0);
            acc[1][0] = __builtin_amdgcn_mfma_f32_16x16x32_bf16(a1, b0,  acc[1][0], 0, 0, 0);
            acc[1][1] = __builtin_amdgcn_mfma_f32_16x16x32_bf16(a1, b1v, acc[1][1], 0, 0, 0);
            acc[1][2] = __builtin_amdgcn_mfma_f32_16x16x32_bf16(a1, b2v, acc[1][2], 0, 0, 0);
        }
    }
    __syncthreads();
    // 2-stage cross-wave reduction in dead S. Partial layout:
    // [wv(0..3)][mt(0..1)][row16][48] floats = 6144 floats (24,576 B).
    float* logitsP = (float*)S;
    float* logitsF = (float*)S + 6144;           // 1536 floats, ends at 30,720 B
    if (wave >= 4) {
        int wv = wave - 4;
#pragma unroll
        for (int mt = 0; mt < 2; mt++)
#pragma unroll
            for (int nt = 0; nt < 3; nt++)
#pragma unroll
                for (int r = 0; r < 4; r++)
                    logitsP[(size_t)(wv * 2 + mt) * 768 + (q * 4 + r) * 48 + nt * 16 + l15] = acc[mt][nt][r];
    }
    __syncthreads();
    if (wave < 4) {
        int wv = wave;
#pragma unroll
        for (int mt = 0; mt < 2; mt++)
#pragma unroll
            for (int nt = 0; nt < 3; nt++)
#pragma unroll
                for (int r = 0; r < 4; r++) {
                    size_t idx = (size_t)(wv * 2 + mt) * 768 + (q * 4 + r) * 48 + nt * 16 + l15;
                    logitsP[idx] += acc[mt][nt][r];
                }
    }
    __syncthreads();
    // final sum over 4 partials, 384 threads (192 per element)
    int tg2 = tid / 192, tl2 = tid - tg2 * 192;
    int tE = tl2 / 12, gE = tl2 - tE * 12;
    if (tid < 384) {
        const float4* P0 = (const float4*)(logitsP + (size_t)(0 * 2 + tg2) * 768);
        const float4* P1 = (const float4*)(logitsP + (size_t)(1 * 2 + tg2) * 768);
        const float4* P2 = (const float4*)(logitsP + (size_t)(2 * 2 + tg2) * 768);
        const float4* P3 = (const float4*)(logitsP + (size_t)(3 * 2 + tg2) * 768);
        float4 p0 = P0[tl2], p1 = P1[tl2], p2 = P2[tl2], p3 = P3[tl2];
        float4 bb = *(const float4*)&b2s[gE * 4];
        float4 r;
        r.x = p0.x + p1.x + p2.x + p3.x + bb.x;
        r.y = p0.y + p1.y + p2.y + p3.y + bb.y;
        r.z = p0.z + p1.z + p2.z + p3.z + bb.z;
        r.w = p0.w + p1.w + p2.w + p3.w + bb.w;
        ((float4*)(logitsF + tg2 * 768))[tl2] = r;
        float lm = (gE == 11) ? r.x : fmaxf(fmaxf(r.x, r.y), fmaxf(r.z, r.w));
        pmax[tg2][tE][gE] = lm;
    }
    __syncthreads();
    if (tid < 384 && gE == 0) {
        float m = pmax[tg2][tE][0];
        for (int i = 1; i < 12; i++) m = fmaxf(m, pmax[tg2][tE][i]);
        mxS[tg2][tE] = m;
    }
    __syncthreads();
    if (tid < 384) {
        float m = mxS[tg2][tE];
        float4 v = ((const float4*)(logitsF + tg2 * 768))[tl2];
        float s;
        if (gE == 11) s = __expf(v.x - m);
        else s = __expf(v.x - m) + __expf(v.y - m) + __expf(v.z - m) + __expf(v.w - m);
        psum[tg2][tE][gE] = s;
    }
    __syncthreads();
    if (tl < nd) {
        float ssum = 0.f;
        for (int i = 0; i < 12; i++) ssum += psum[tg][tl][i];
        float m = mxS[tg][tl];
        int dac = dacsS[tg][tl];
        float ld = logitsF[tg * 768 + tl * 48 + dac];
        float ce = -(ld - m - logf(ssum));
        ceArr[tg][tl] = ce * (float)multsS[tg][tl];
    }
    __syncthreads();
    if (tl == 0) {
        float s = 0.f;
        for (int t = 0; t < nd; t++) s += ceArr[tg][t];
        loss_out[bp * NB + tg] = s / (float)atS[tg];
    }
}

// ---------------------------------------------------------------------------
// Deterministic final reduction over 4096 per-b losses.
// 512 threads, float4 loads: 2 dependent loads/thread instead of 16 scalar
// (this kernel is a single-block latency tail; shorten its load chain).
// ---------------------------------------------------------------------------
__global__ __launch_bounds__(512) void reduce_loss(const float* __restrict__ loss,
                                                   float* __restrict__ out) {
    int tid = threadIdx.x;  // 512
    const float4* l4 = (const float4*)loss;     // 1024 float4
    float4 a = l4[tid];
    float4 b = l4[512 + tid];
    float s = (a.x + a.y + a.z + a.w) + (b.x + b.y + b.z + b.w);
    for (int off = 32; off > 0; off >>= 1) s += __shfl_down(s, off, 64);
    __shared__ float wsum[8];
    if ((tid & 63) == 0) wsum[tid >> 6] = s;
    __syncthreads();
    if (tid == 0) {
        float t = 0.f;
        for (int i = 0; i < 8; i++) t += wsum[i];
        out[0] = t * (1.0f / (float)BATCH);
    }
}

// ---------------------------------------------------------------------------
extern "C" void kernel_launch(void* const* d_in, const int* in_sizes, int n_in,
                              void* d_out, int out_size, void* d_ws, size_t ws_size,
                              hipStream_t stream) {
    const float* fc_input = (const float*)d_in[0];
    const float* camera   = (const float*)d_in[1];
    const int*   fb       = (const int*)d_in[2];
    const int*   lr       = (const int*)d_in[3];
    const int*   jp       = (const int*)d_in[4];
    const int*   ss       = (const int*)d_in[5];
    const int*   at       = (const int*)d_in[6];
    const float* W1       = (const float*)d_in[7];
    const float* b1       = (const float*)d_in[8];
    const float* W2       = (const float*)d_in[9];
    const float* b2       = (const float*)d_in[10];
    float* out = (float*)d_out;

    char* ws = (char*)d_ws;
    unsigned short* Ab   = (unsigned short*)(ws);                       //  8,388,608 B
    unsigned short* Wt   = (unsigned short*)(ws + 8388608);             //  4,194,304 B
    float*          baseB= (float*)(ws + 12582912);                     // 33,554,432 B
    StepMeta*       meta = (StepMeta*)(ws + 46137344);                  //  2,097,152 B
    int2*           hdr  = (int2*)(ws + 48234496);                      //     32,768 B
    float*          lossB= (float*)(ws + 48267264);                     //     16,384 B
    unsigned short* W2T  = (unsigned short*)(ws + 48283648);            //    196,608 B

    prep_kernel<<<4096 + 2048 + 128 + 16, 256, 0, stream>>>(fc_input, Ab, W1, Wt, W2, W2T,
                                                            camera, fb, lr, jp, ss, at, meta, hdr);
    gemm_base<<<dim3(HID / 64, BATCH / 128), 256, 0, stream>>>(Ab, Wt, W1, b1, baseB);
    fused_mlp<<<BATCH / NB, 512, 0, stream>>>(baseB, W1, W2T, b2, meta, hdr, lossB);
    reduce_loss<<<1, 512, 0, stream>>>(lossB, out);
}

// Round 15
// 192.735 us; speedup vs baseline: 1.1021x; 1.0834x over previous
//
#include <hip/hip_runtime.h>

// Problem constants
#define BATCH 4096
#define NI 1024
#define HID 2048
#define TSTEPS 20
#define NA 45
#define TW 512    // fused j-tile width (4 tiles over HID)
#define SROW 520  // S row stride in bf16 elems (512 + 8 pad)
#define MAXS 16   // max distinct alive states per batch element (proven <= 15)
#define NB 4      // batch elements per fused_mlp block

typedef __bf16 bf16x8 __attribute__((ext_vector_type(8)));
typedef float floatx4 __attribute__((ext_vector_type(4)));

struct StepMeta {
    float ac0, ac1, delta, chosen;
    int chg;    // (oldCol<<8)|newCol applied entering this state, or -1
    int dac, mult, pad;
};

__device__ __forceinline__ unsigned short f2bf(float x) {
    union { float f; unsigned int u; } un; un.f = x;
    unsigned int r = un.u + 0x7FFFu + ((un.u >> 16) & 1u);
    return (unsigned short)(r >> 16);
}

__device__ __forceinline__ float4 f4add(float4 a, float4 b) {
    return make_float4(a.x + b.x, a.y + b.y, a.z + b.z, a.w + b.w);
}

// ---------------------------------------------------------------------------
// Per-batch-element 20-step state machine (exact fp32 replication),
// COMPRESSED: emits only distinct alive states; trailing fixed point gets a
// multiplicity; post-commit steps dropped. nd <= 15 < MAXS.
// Swap (chg>=0) states are the CONTIGUOUS PREFIX 1..ns.
// ---------------------------------------------------------------------------
__device__ void scan_one(int b, const float* __restrict__ camera,
                         const int* __restrict__ fb_in, const int* __restrict__ lr_in,
                         const int* __restrict__ jp_in, const int* __restrict__ ss_in,
                         const int* __restrict__ at_in, StepMeta* __restrict__ meta,
                         int2* __restrict__ hdr) {
    float cam0 = camera[2 * b], cam1 = camera[2 * b + 1];
    int afb = fb_in[b], alr = lr_in[b], ajp = jp_in[b], ass = ss_in[b], aat = at_in[b];
    float ac0 = 0.f, ac1 = 0.f, delta = 0.0625f;  // MIN_DELTA = 0.5/8
    int rfb = 0, rlr = 0, rjp = 0, rss = 0, rat = 0;
    bool chosen = false;
    int cam_steps = 0;
    int chgPending = -1;
    bool camzero = (fabsf(cam0) < 1e-5f) && (fabsf(cam1) < 1e-5f);
    int nd = 0, aliveTot = 0;
    float lac0 = 0.f, lac1 = 0.f, ldelta = 0.f, lchosen = 0.f;
    int ldac = -1000;
    for (int t = 0; t < TSTEPS; t++) {
        StepMeta m;
        m.ac0 = ac0; m.ac1 = ac1; m.delta = delta; m.chosen = chosen ? 1.f : 0.f;
        m.chg = chgPending; chgPending = -1;
        bool commit = (camzero || cam_steps >= 6) &&
                      rfb == afb && rlr == alr && rjp == ajp && rss == ass && rat == aat;
        int dac = 0; bool modified = commit;
        if (!modified && rfb != afb) { dac = (afb == 0 ? rfb - 1 + 6  : afb - 1 + 6 ); chgPending = ((2  + rfb) << 8) | (2  + afb); rfb = afb; modified = true; }
        if (!modified && rlr != alr) { dac = (alr == 0 ? rlr - 1 + 8  : alr - 1 + 8 ); chgPending = ((5  + rlr) << 8) | (5  + alr); rlr = alr; modified = true; }
        if (!modified && rjp != ajp) { dac = (ajp == 0 ? rjp - 1 + 10 : ajp - 1 + 10); chgPending = ((8  + rjp) << 8) | (8  + ajp); rjp = ajp; modified = true; }
        if (!modified && rss != ass) { dac = (ass == 0 ? rss - 1 + 11 : ass - 1 + 11); chgPending = ((10 + rss) << 8) | (10 + ass); rss = ass; modified = true; }
        if (!modified && rat != aat) { dac = (aat == 0 ? rat - 1 + 14 : aat - 1 + 14); chgPending = ((14 + rat) << 8) | (14 + aat); rat = aat; modified = true; }
        // NOTE: reference compares BOTH cam0 and cam1 against ac0 (replicated as-is)
        if (!modified && !chosen &&
            (fabsf(cam0 - ac0) > delta * 2.f || fabsf(cam1 - ac0) > delta * 2.f)) {
            dac = 5; delta = fminf(delta * 2.f, 0.5f); modified = true;
        }
        if (!modified) {
            bool incX = cam0 >= ac0, incY = cam1 >= ac1;
            dac = 1 + (incX ? 1 : 0) + (incY ? 2 : 0);
            ac0 += incX ? delta : -delta;
            ac1 += incY ? delta : -delta;
            delta *= 0.5f;
            chosen = true;
            cam_steps++;
        }
        m.dac = dac; m.mult = 1; m.pad = 0;
        // trailing fixed-point detection: identical state => identical forever
        if (nd > 0 && m.chg < 0 && !commit &&
            m.ac0 == lac0 && m.ac1 == lac1 && m.delta == ldelta &&
            m.chosen == lchosen && dac == ldac) {
            meta[b * MAXS + nd - 1].mult = 1 + (TSTEPS - t);
            aliveTot += (TSTEPS - t);
            break;
        }
        meta[b * MAXS + nd] = m;
        lac0 = m.ac0; lac1 = m.ac1; ldelta = m.delta; lchosen = m.chosen; ldac = dac;
        nd++; aliveTot++;
        if (commit) break;  // all remaining steps dead (alive=0 -> ce masked)
    }
    hdr[b] = make_int2(nd, aliveTot);
}

// ---------------------------------------------------------------------------
// Merged prep: convert_fc (blocks [0,4096)), transpose_w1 ([4096,6144)),
// convert_w2 ([6144,6272), 128-way parallel), scan FSM ([6272,6288)).
// ---------------------------------------------------------------------------
__global__ void prep_kernel(const float* __restrict__ fc, unsigned short* __restrict__ Ab,
                            const float* __restrict__ W1, unsigned short* __restrict__ Wt,
                            const float* __restrict__ W2, unsigned short* __restrict__ W2T,
                            const float* __restrict__ camera,
                            const int* __restrict__ fb_in, const int* __restrict__ lr_in,
                            const int* __restrict__ jp_in, const int* __restrict__ ss_in,
                            const int* __restrict__ at_in, StepMeta* __restrict__ meta,
                            int2* __restrict__ hdr) {
    __shared__ float tile[32][33];
    int bid = blockIdx.x, tid = threadIdx.x;
    if (bid < 4096) {
        int idx = bid * 256 + tid;  // covers BATCH*NI/4
        float4 v = ((const float4*)fc)[idx];
        ushort4 o;
        o.x = f2bf(v.x); o.y = f2bf(v.y); o.z = f2bf(v.z); o.w = f2bf(v.w);
        ((ushort4*)Ab)[idx] = o;
    } else if (bid < 6144) {
        int b2 = bid - 4096;
        int k0 = (b2 & 31) * 32, n0 = (b2 >> 5) * 32;
        int tx = tid & 31, ty = tid >> 5;  // (32, 8)
        for (int i = 0; i < 4; i++)
            tile[ty + 8 * i][tx] = W1[(size_t)(k0 + ty + 8 * i) * HID + n0 + tx];
        __syncthreads();
        for (int i = 0; i < 4; i++) {
            int n = ty + 8 * i;
            Wt[(size_t)(n0 + n) * NI + k0 + tx] = f2bf(tile[tx][n]);
        }
    } else if (bid < 6272) {
        int bid2 = bid - 6144;                 // 0..127
        int k = bid2 * 16 + (tid >> 4);        // 0..2047
        int nn = tid & 15;
#pragma unroll
        for (int i = 0; i < 3; i++) {
            int n = nn * 3 + i;                // 0..47
            W2T[(size_t)n * HID + k] = (n < NA) ? f2bf(W2[(size_t)k * NA + n]) : (unsigned short)0;
        }
    } else {
        int b = (bid - 6272) * 256 + tid;      // 0..4095
        scan_one(b, camera, fb_in, lr_in, jp_in, ss_in, at_in, meta, hdr);
    }
}

// ---------------------------------------------------------------------------
// GEMM: base[4096][2048] = A @ W1[:1024] (bf16 MFMA) + t=0-constant
// epilogue. R12 configuration (measured best): 128x64 tile, 256 threads /
// 4 waves (2x2), linear dispatch, 1024 blocks = 4 blocks/CU. BK=64 +
// both-sides swizzle (rule #21): linear gload_lds dest + pre-swizzled
// SOURCE chunk (part ^= row&7) + matching XOR on the read. absmax 0.0.
// ---------------------------------------------------------------------------
__global__ __launch_bounds__(256) void gemm_base(const unsigned short* __restrict__ Ab,
                                                 const unsigned short* __restrict__ Wt,
                                                 const float* __restrict__ W1,
                                                 const float* __restrict__ b1,
                                                 float* __restrict__ C) {
    __shared__ __align__(16) __bf16 At[128 * 64];   // 16 KB
    __shared__ __align__(16) __bf16 Bt[64 * 64];    //  8 KB
    int bn = blockIdx.x, bm = blockIdx.y;
    int m0 = bm * 128, n0 = bn * 64;
    int tid = threadIdx.x;
    int wave = tid >> 6, lane = tid & 63;
    int wr = wave >> 1, wc = wave & 1;           // 2 x 2 wave grid
    int l15 = lane & 15, q = lane >> 4;
    floatx4 acc[4][2];
    for (int a = 0; a < 4; a++) for (int c = 0; c < 2; c++) acc[a][c] = (floatx4){0.f, 0.f, 0.f, 0.f};
    for (int k0 = 0; k0 < NI; k0 += 64) {
        __syncthreads();
#pragma unroll
        for (int i = 0; i < 4; i++) {              // A: 1024 16B-chunks
            int c = i * 256 + tid;
            int row = c >> 3;                      // 0..127
            int part = (c & 7) ^ (row & 7);        // pre-swizzled source slot
            const unsigned short* gA = &Ab[(size_t)(m0 + row) * NI + k0 + part * 8];
            __builtin_amdgcn_global_load_lds(
                (const __attribute__((address_space(1))) unsigned int*)gA,
                (__attribute__((address_space(3))) unsigned int*)&At[c * 8], 16, 0, 0);
        }
#pragma unroll
        for (int i = 0; i < 2; i++) {              // B: 512 16B-chunks
            int c = i * 256 + tid;
            int row = c >> 3;                      // 0..63
            int part = (c & 7) ^ (row & 7);
            const unsigned short* gB = &Wt[(size_t)(n0 + row) * NI + k0 + part * 8];
            __builtin_amdgcn_global_load_lds(
                (const __attribute__((address_space(1))) unsigned int*)gB,
                (__attribute__((address_space(3))) unsigned int*)&Bt[c * 8], 16, 0, 0);
        }
        __syncthreads();
#pragma unroll
        for (int ks = 0; ks < 2; ks++) {
            bf16x8 af[4], bf[2];
            for (int mr = 0; mr < 4; mr++) {
                int row = wr * 64 + mr * 16 + l15;
                int idx = (row * 64 + ks * 32 + q * 8) ^ ((row & 7) << 3);
                af[mr] = *(const bf16x8*)&At[idx];
            }
            for (int nc = 0; nc < 2; nc++) {
                int row = wc * 32 + nc * 16 + l15;
                int idx = (row * 64 + ks * 32 + q * 8) ^ ((row & 7) << 3);
                bf[nc] = *(const bf16x8*)&Bt[idx];
            }
            for (int mr = 0; mr < 4; mr++)
                for (int nc = 0; nc < 2; nc++)
                    acc[mr][nc] = __builtin_amdgcn_mfma_f32_16x16x32_bf16(af[mr], bf[nc], acc[mr][nc], 0, 0, 0);
        }
    }
    for (int nc = 0; nc < 2; nc++) {
        int col = n0 + wc * 32 + nc * 16 + l15;
        const float* We = W1 + (size_t)NI * HID + col;
        float cv = b1[col] + We[2 * HID] + We[5 * HID] + We[8 * HID] + We[10 * HID]
                 + We[14 * HID] + 0.0625f * We[46 * HID];
        for (int mr = 0; mr < 4; mr++)
            for (int r = 0; r < 4; r++) {
                int row = m0 + wr * 64 + mr * 16 + q * 4 + r;
                C[(size_t)row * HID + col] = acc[mr][nc][r] + cv;
            }
    }
}

// ---------------------------------------------------------------------------
// Fused MLP + CE over COMPRESSED states, NB=4 batch elements per block.
// Phase A: tg = tid>>7 (4 groups of 128 threads), 4 float4-columns per
// thread per jt (same per-column load/ALU counts and ILP as the proven R10
// structure). Phase B: ONE M=64 tile — all 4 elements share every W2T
// B-fragment, halving W2T load-instructions per element vs R10 (the lever
// family behind every win this session: R3 -12us, R10 -6us).
// S = 4x16 rows x 520 = 66.5 KB -> 2 blocks/CU (proven envelope).
// __launch_bounds__(512, 2): VGPR cap 256 (R8: tighter caps force spill;
// WRITE_SIZE is the tripwire, must stay ~64 KB).
// ---------------------------------------------------------------------------
__global__ __launch_bounds__(512, 2) void fused_mlp(const float* __restrict__ base,
                                                 const float* __restrict__ W1,
                                                 const unsigned short* __restrict__ W2T,
                                                 const float* __restrict__ b2,
                                                 const StepMeta* __restrict__ meta,
                                                 const int2* __restrict__ hdr,
                                                 float* __restrict__ loss_out) {
    __shared__ __align__(16) __bf16 S[NB * MAXS * SROW];   // 66,560 B; pad rows zero
    __shared__ __align__(16) float4 u4s[NB][MAXS];         // (ac0, ac1, delta-d0, chosen)
    __shared__ int chgs[NB][MAXS], dacsS[NB][MAXS], multsS[NB][MAXS];
    __shared__ int swapL[NB][5], nsS[NB], ndS[NB], atS[NB];
    __shared__ float b2s[48];
    __shared__ float ceArr[NB][MAXS];
    __shared__ float pmax[NB][MAXS][12], psum[NB][MAXS][12], mxS[NB][MAXS];

    int bp = blockIdx.x, tid = threadIdx.x;
    int tg = tid >> 7, tl = tid & 127;           // group (=b within quad), local tid
    int wave = tid >> 6, lane = tid & 63, l15 = lane & 15, q = lane >> 4;

    if (tl == 0) {
        int2 hd = hdr[bp * NB + tg];
        ndS[tg] = hd.x; atS[tg] = hd.y;
    }
    if (tl < MAXS) {
        StepMeta m = meta[(size_t)(bp * NB + tg) * MAXS + tl];
        u4s[tg][tl] = make_float4(m.ac0, m.ac1, m.delta - 0.0625f, m.chosen);
        chgs[tg][tl] = m.chg; dacsS[tg][tl] = m.dac; multsS[tg][tl] = m.mult;
    }
    if (tid >= 64 && tid < 112) {
        int n = tid - 64;
        b2s[n] = (n < NA) ? b2[n] : 0.f;
    }
    __syncthreads();
    if (tl == 0) {
        int ns = 0, nd = ndS[tg];
        for (int s = 0; s < nd; s++)
            if (chgs[tg][s] >= 0) swapL[tg][ns++] = chgs[tg][s];
        nsS[tg] = ns;
        for (; ns < 5; ns++) swapL[tg][ns] = 0;
    }
    // zero the MFMA padding rows (row = 1040 B = 65 uint4) for all 4 elements
    {
        uint4 zz = make_uint4(0, 0, 0, 0);
#pragma unroll
        for (int e = 0; e < NB; e++) {
            int nde = ndS[e];
            uint4* z = (uint4*)&S[(size_t)(e * MAXS + nde) * SROW];
            int n16 = (MAXS - nde) * 65;
            for (int i = tid; i < n16; i += 512) z[i] = zz;
        }
    }
    __syncthreads();

    const float* Wx = W1 + (size_t)NI * HID;
    const __bf16* Wb = (const __bf16*)W2T;
    floatx4 acc[4][3];                           // [element][n-tile]
    for (int a = 0; a < 4; a++) for (int c = 0; c < 3; c++) acc[a][c] = (floatx4){0.f, 0.f, 0.f, 0.f};

    int nd = __builtin_amdgcn_readfirstlane(ndS[tg]);
    int ns = __builtin_amdgcn_readfirstlane(nsS[tg]);
    int cA = __builtin_amdgcn_readfirstlane(swapL[tg][0]);
    int cB = __builtin_amdgcn_readfirstlane(swapL[tg][1]);
    int cC = __builtin_amdgcn_readfirstlane(swapL[tg][2]);
    int cD = __builtin_amdgcn_readfirstlane(swapL[tg][3]);
    int cE = __builtin_amdgcn_readfirstlane(swapL[tg][4]);

    for (int jt = 0; jt < 4; jt++) {
        if (jt) __syncthreads();                 // phase-B readers of prev tile done
        int j = jt * TW + 4 * tl;
        // hoisted loads (float4, 4 columns): w-vectors, base, ALL swap rows
        float4 w0  = *(const float4*)&Wx[j];
        float4 w1  = *(const float4*)&Wx[HID + j];
        float4 wdl = *(const float4*)&Wx[46 * HID + j];
        float4 wch = *(const float4*)&Wx[47 * HID + j];
        float4 hb  = *(const float4*)&base[(size_t)(bp * NB + tg) * HID + j];
        float4 dA = {0,0,0,0}, dB = {0,0,0,0}, dC = {0,0,0,0}, dD = {0,0,0,0}, dE = {0,0,0,0};
        if (ns > 0) { float4 n_ = *(const float4*)&Wx[(size_t)(cA & 255) * HID + j], o_ = *(const float4*)&Wx[(size_t)(cA >> 8) * HID + j];
                      dA = make_float4(n_.x - o_.x, n_.y - o_.y, n_.z - o_.z, n_.w - o_.w); }
        if (ns > 1) { float4 n_ = *(const float4*)&Wx[(size_t)(cB & 255) * HID + j], o_ = *(const float4*)&Wx[(size_t)(cB >> 8) * HID + j];
                      dB = make_float4(n_.x - o_.x, n_.y - o_.y, n_.z - o_.z, n_.w - o_.w); }
        if (ns > 2) { float4 n_ = *(const float4*)&Wx[(size_t)(cC & 255) * HID + j], o_ = *(const float4*)&Wx[(size_t)(cC >> 8) * HID + j];
                      dC = make_float4(n_.x - o_.x, n_.y - o_.y, n_.z - o_.z, n_.w - o_.w); }
        if (ns > 3) { float4 n_ = *(const float4*)&Wx[(size_t)(cD & 255) * HID + j], o_ = *(const float4*)&Wx[(size_t)(cD >> 8) * HID + j];
                      dD = make_float4(n_.x - o_.x, n_.y - o_.y, n_.z - o_.z, n_.w - o_.w); }
        if (ns > 4) { float4 n_ = *(const float4*)&Wx[(size_t)(cE & 255) * HID + j], o_ = *(const float4*)&Wx[(size_t)(cE >> 8) * HID + j];
                      dE = make_float4(n_.x - o_.x, n_.y - o_.y, n_.z - o_.z, n_.w - o_.w); }

        // one silu state over 4 columns: h = ((b + u.x*w0) + (u.y*w1 + u.z*wdl)) + u.w*wch
        auto compute1 = [&](int s, float4 b) {
            float4 u = u4s[tg][s];
            float h0 = fmaf(u.w, wch.x, fmaf(u.x, w0.x, b.x)) + fmaf(u.z, wdl.x, u.y * w1.x);
            float h1 = fmaf(u.w, wch.y, fmaf(u.x, w0.y, b.y)) + fmaf(u.z, wdl.y, u.y * w1.y);
            float h2 = fmaf(u.w, wch.z, fmaf(u.x, w0.z, b.z)) + fmaf(u.z, wdl.z, u.y * w1.z);
            float h3 = fmaf(u.w, wch.w, fmaf(u.x, w0.w, b.w)) + fmaf(u.z, wdl.w, u.y * w1.w);
            float s0 = h0 * __builtin_amdgcn_rcpf(1.f + __expf(-h0));
            float s1 = h1 * __builtin_amdgcn_rcpf(1.f + __expf(-h1));
            float s2 = h2 * __builtin_amdgcn_rcpf(1.f + __expf(-h2));
            float s3 = h3 * __builtin_amdgcn_rcpf(1.f + __expf(-h3));
            union { uint2 v; __bf16 h[4]; } pk;
            pk.h[0] = (__bf16)s0; pk.h[1] = (__bf16)s1;   // v_cvt_pk_bf16_f32 (RNE)
            pk.h[2] = (__bf16)s2; pk.h[3] = (__bf16)s3;
            *(uint2*)&S[(size_t)(tg * MAXS + s) * SROW + 4 * tl] = pk.v;
        };

        // swap-prefix states (contiguous, compile-time unrolled; ns uniform)
        float4 sw = {0,0,0,0};
        compute1(0, hb);
        if (ns > 0) { sw = f4add(sw, dA); compute1(1, f4add(hb, sw)); }
        if (ns > 1) { sw = f4add(sw, dB); compute1(2, f4add(hb, sw)); }
        if (ns > 2) { sw = f4add(sw, dC); compute1(3, f4add(hb, sw)); }
        if (ns > 3) { sw = f4add(sw, dD); compute1(4, f4add(hb, sw)); }
        if (ns > 4) { sw = f4add(sw, dE); compute1(5, f4add(hb, sw)); }
        // tail states (no swaps): 2 per iteration -> 8 independent silu chains
        float4 bxv = f4add(hb, sw);
        int s = ns + 1;
        for (; s + 1 < nd; s += 2) {
            compute1(s, bxv);
            compute1(s + 1, bxv);
        }
        if (s < nd) compute1(s, bxv);

        __syncthreads();
        // Phase B: 8 waves split K (TW=512 -> 16 chunks, wave w takes {w, w+8});
        // M=64 rows: ALL FOUR elements share each W2T B-fragment.
#pragma unroll
        for (int i = 0; i < 2; i++) {
            int kc = (wave + 8 * i) * 32 + q * 8;            // 0..511
            bf16x8 a0 = *(const bf16x8*)&S[(size_t)l15 * SROW + kc];
            bf16x8 a1 = *(const bf16x8*)&S[(size_t)(MAXS + l15) * SROW + kc];
            bf16x8 a2 = *(const bf16x8*)&S[(size_t)(2 * MAXS + l15) * SROW + kc];
            bf16x8 a3 = *(const bf16x8*)&S[(size_t)(3 * MAXS + l15) * SROW + kc];
            int kg = jt * TW + kc;
            bf16x8 b0  = *(const bf16x8*)&Wb[(size_t)l15 * HID + kg];
            bf16x8 b1v = *(const bf16x8*)&Wb[(size_t)(16 + l15) * HID + kg];
            bf16x8 b2v = *(const bf16x8*)&Wb[(size_t)(32 + l15) * HID + kg];
            acc[0][0] = __builtin_amdgcn_mfma_f32_16x16x32_bf16(a0, b0,  acc[0][0], 0, 0, 0);
            acc[0][1] = __builtin_amdgcn_mfma_f32_16x16x32_bf16(a0, b1v, acc[0][1], 0, 0, 0);
            acc[0][2] = __builtin_amdgcn_mfma_f32_16x16x32_bf16(a0, b2v, acc[0][2], 0, 0, 0);
            acc[1][0] = __builtin_amdgcn_mfma_f32_16x16x32_bf16(a1, b0,  acc[1][0], 0, 0, 0);
            acc[1][1] = __builtin_amdgcn_mfma_f32_16x16x32_bf16(a1, b1v, acc[1][1], 0, 0, 0);
            acc[1][2] = __builtin_amdgcn_mfma_f32_16x16x32_bf16(a1, b2v, acc[1][2], 0, 0, 0);
            acc[2][0] = __builtin_amdgcn_mfma_f32_16x16x32_bf16(a2, b0,  acc[2][0], 0, 0, 0);
            acc[2][1] = __builtin_amdgcn_mfma_f32_16x16x32_bf16(a2, b1v, acc[2][1], 0, 0, 0);
            acc[2][2] = __builtin_amdgcn_mfma_f32_16x16x32_bf16(a2, b2v, acc[2][2], 0, 0, 0);
            acc[3][0] = __builtin_amdgcn_mfma_f32_16x16x32_bf16(a3, b0,  acc[3][0], 0, 0, 0);
            acc[3][1] = __builtin_amdgcn_mfma_f32_16x16x32_bf16(a3, b1v, acc[3][1], 0, 0, 0);
            acc[3][2] = __builtin_amdgcn_mfma_f32_16x16x32_bf16(a3, b2v, acc[3][2], 0, 0, 0);
        }
    }
    __syncthreads();
    // 2-stage cross-wave reduction in dead S.
    // Partial layout: [wv(0..3)][elem(0..3)][row16][48] = 12288 floats (49,152 B).
    float* logitsP = (float*)S;
    float* logitsF = (float*)S + 12288;          // 3072 floats, ends at 61,440 B
    if (wave >= 4) {
        int wv = wave - 4;
#pragma unroll
        for (int e = 0; e < 4; e++)
#pragma unroll
            for (int nt = 0; nt < 3; nt++)
#pragma unroll
                for (int r = 0; r < 4; r++)
                    logitsP[(size_t)(wv * 4 + e) * 768 + (q * 4 + r) * 48 + nt * 16 + l15] = acc[e][nt][r];
    }
    __syncthreads();
    if (wave < 4) {
        int wv = wave;
#pragma unroll
        for (int e = 0; e < 4; e++)
#pragma unroll
            for (int nt = 0; nt < 3; nt++)
#pragma unroll
                for (int r = 0; r < 4; r++) {
                    size_t idx = (size_t)(wv * 4 + e) * 768 + (q * 4 + r) * 48 + nt * 16 + l15;
                    logitsP[idx] += acc[e][nt][r];
                }
    }
    __syncthreads();
    // final sum over 4 partials: 768 float4 entries (4 elem x 192), strided loop
    for (int i = tid; i < 768; i += 512) {
        int e = i / 192, rem = i - e * 192;
        int row = rem / 12, gE = rem - row * 12;
        const float4* P0 = (const float4*)(logitsP + (size_t)(0 * 4 + e) * 768);
        const float4* P1 = (const float4*)(logitsP + (size_t)(1 * 4 + e) * 768);
        const float4* P2 = (const float4*)(logitsP + (size_t)(2 * 4 + e) * 768);
        const float4* P3 = (const float4*)(logitsP + (size_t)(3 * 4 + e) * 768);
        float4 p0 = P0[rem], p1 = P1[rem], p2 = P2[rem], p3 = P3[rem];
        float4 bb = *(const float4*)&b2s[gE * 4];
        float4 r;
        r.x = p0.x + p1.x + p2.x + p3.x + bb.x;
        r.y = p0.y + p1.y + p2.y + p3.y + bb.y;
        r.z = p0.z + p1.z + p2.z + p3.z + bb.z;
        r.w = p0.w + p1.w + p2.w + p3.w + bb.w;
        ((float4*)(logitsF + (size_t)e * 768))[rem] = r;
        float lm = (gE == 11) ? r.x : fmaxf(fmaxf(r.x, r.y), fmaxf(r.z, r.w));
        pmax[e][row][gE] = lm;
    }
    __syncthreads();
    if (tid < 64) {                              // 4 elem x 16 rows
        int e = tid >> 4, row = tid & 15;
        float m = pmax[e][row][0];
        for (int i = 1; i < 12; i++) m = fmaxf(m, pmax[e][row][i]);
        mxS[e][row] = m;
    }
    __syncthreads();
    for (int i = tid; i < 768; i += 512) {
        int e = i / 192, rem = i - e * 192;
        int row = rem / 12, gE = rem - row * 12;
        float m = mxS[e][row];
        float4 v = ((const float4*)(logitsF + (size_t)e * 768))[rem];
        float s;
        if (gE == 11) s = __expf(v.x - m);
        else s = __expf(v.x - m) + __expf(v.y - m) + __expf(v.z - m) + __expf(v.w - m);
        psum[e][row][gE] = s;
    }
    __syncthreads();
    if (tl < nd) {
        float ssum = 0.f;
        for (int i = 0; i < 12; i++) ssum += psum[tg][tl][i];
        float m = mxS[tg][tl];
        int dac = dacsS[tg][tl];
        float ld = logitsF[(size_t)tg * 768 + tl * 48 + dac];
        float ce = -(ld - m - logf(ssum));
        ceArr[tg][tl] = ce * (float)multsS[tg][tl];
    }
    __syncthreads();
    if (tl == 0) {
        float s = 0.f;
        for (int t = 0; t < nd; t++) s += ceArr[tg][t];
        loss_out[bp * NB + tg] = s / (float)atS[tg];
    }
}

// ---------------------------------------------------------------------------
// Deterministic final reduction over 4096 per-b losses.
// 512 threads, float4 loads (single-block latency tail; short load chain).
// ---------------------------------------------------------------------------
__global__ __launch_bounds__(512) void reduce_loss(const float* __restrict__ loss,
                                                   float* __restrict__ out) {
    int tid = threadIdx.x;  // 512
    const float4* l4 = (const float4*)loss;     // 1024 float4
    float4 a = l4[tid];
    float4 b = l4[512 + tid];
    float s = (a.x + a.y + a.z + a.w) + (b.x + b.y + b.z + b.w);
    for (int off = 32; off > 0; off >>= 1) s += __shfl_down(s, off, 64);
    __shared__ float wsum[8];
    if ((tid & 63) == 0) wsum[tid >> 6] = s;
    __syncthreads();
    if (tid == 0) {
        float t = 0.f;
        for (int i = 0; i < 8; i++) t += wsum[i];
        out[0] = t * (1.0f / (float)BATCH);
    }
}

// ---------------------------------------------------------------------------
extern "C" void kernel_launch(void* const* d_in, const int* in_sizes, int n_in,
                              void* d_out, int out_size, void* d_ws, size_t ws_size,
                              hipStream_t stream) {
    const float* fc_input = (const float*)d_in[0];
    const float* camera   = (const float*)d_in[1];
    const int*   fb       = (const int*)d_in[2];
    const int*   lr       = (const int*)d_in[3];
    const int*   jp       = (const int*)d_in[4];
    const int*   ss       = (const int*)d_in[5];
    const int*   at       = (const int*)d_in[6];
    const float* W1       = (const float*)d_in[7];
    const float* b1       = (const float*)d_in[8];
    const float* W2       = (const float*)d_in[9];
    const float* b2       = (const float*)d_in[10];
    float* out = (float*)d_out;

    char* ws = (char*)d_ws;
    unsigned short* Ab   = (unsigned short*)(ws);                       //  8,388,608 B
    unsigned short* Wt   = (unsigned short*)(ws + 8388608);             //  4,194,304 B
    float*          baseB= (float*)(ws + 12582912);                     // 33,554,432 B
    StepMeta*       meta = (StepMeta*)(ws + 46137344);                  //  2,097,152 B
    int2*           hdr  = (int2*)(ws + 48234496);                      //     32,768 B
    float*          lossB= (float*)(ws + 48267264);                     //     16,384 B
    unsigned short* W2T  = (unsigned short*)(ws + 48283648);            //    196,608 B

    prep_kernel<<<4096 + 2048 + 128 + 16, 256, 0, stream>>>(fc_input, Ab, W1, Wt, W2, W2T,
                                                            camera, fb, lr, jp, ss, at, meta, hdr);
    gemm_base<<<dim3(HID / 64, BATCH / 128), 256, 0, stream>>>(Ab, Wt, W1, b1, baseB);
    fused_mlp<<<BATCH / NB, 512, 0, stream>>>(baseB, W1, W2T, b2, meta, hdr, lossB);
    reduce_loss<<<1, 512, 0, stream>>>(lossB, out);
}